// Round 15
// baseline (97.426 us; speedup 1.0000x reference)
//
#include <hip/hip_runtime.h>
#include <hip/hip_fp16.h>

#define NBC 14
#define NAC 45
#define KF  52
#define RHO 0.05f
#define TT  4096
#define BB  64
#define CHC 64           // outputs per chain
#define WU  44           // warmup steps
#define NPAIR 32         // chunk pairs per batch
#define NTW (WU + CHC)   // 108 steps per chain
#define SPAN (WU + 2*CHC)// 172: xf range covers both chains
#define XPAD 176         // xf row stride (halfs), mult of 4
#define RING 52          // logical ring slots (exact window)
#define RINGP 54         // physical row stride in u32 (<=3-way banks)
#define LOG2E 1.44269504f
#define XF_BYTES ((size_t)BB * NBC * TT * 2)

typedef __fp16 v2h __attribute__((ext_vector_type(2)));
typedef float  f2  __attribute__((ext_vector_type(2)));
typedef int    i2v __attribute__((ext_vector_type(2)));

__device__ __forceinline__ v2h bch(unsigned u) { return __builtin_bit_cast(v2h, u); }
__device__ __forceinline__ unsigned bcu(v2h h) { return __builtin_bit_cast(unsigned, h); }
__device__ __forceinline__ v2h pk2(float lo, float hi) {
#if __has_builtin(__builtin_amdgcn_cvt_pkrtz)
  return __builtin_bit_cast(v2h, __builtin_amdgcn_cvt_pkrtz(lo, hi));
#else
  v2h r; r[0] = (__fp16)lo; r[1] = (__fp16)hi; return r;
#endif
}
__device__ __forceinline__ v2h xsum16h(v2h v) {
#if __has_builtin(__builtin_amdgcn_permlane16_swap)
  i2v r = __builtin_amdgcn_permlane16_swap((int)bcu(v), (int)bcu(v), false, false);
  return bch((unsigned)r[0]) + bch((unsigned)r[1]);
#else
  return v + bch((unsigned)__builtin_amdgcn_ds_swizzle((int)bcu(v), (16 << 10) | 0x1f));
#endif
}
__device__ __forceinline__ v2h xsum32h(v2h v) {
#if __has_builtin(__builtin_amdgcn_permlane32_swap)
  i2v r = __builtin_amdgcn_permlane32_swap((int)bcu(v), (int)bcu(v), false, false);
  return bch((unsigned)r[0]) + bch((unsigned)r[1]);
#else
  return v + bch((unsigned)__shfl_xor((int)bcu(v), 32));
#endif
}
__device__ __forceinline__ float exp2_f(float x) {
#if __has_builtin(__builtin_amdgcn_exp2f)
  return __builtin_amdgcn_exp2f(x);
#else
  return exp2f(x);
#endif
}

// ---------------- conv pre-pass: xf[b][c][t] for all t ----------------
__global__ __launch_bounds__(256)
void conv_kernel(const float* __restrict__ x, const float* __restrict__ bck,
                 __half* __restrict__ xfg) {
  __shared__ float xs[256 + KF];        // tile + halo
  const int tid  = threadIdx.x;
  const int b    = blockIdx.x >> 4;     // 16 tiles of 256
  const int t0   = (blockIdx.x & 15) << 8;
  for (int i = tid; i < 256 + KF - 1; i += 256) {
    int gt = t0 - (KF - 1) + i;
    xs[i] = (gt >= 0) ? x[b * TT + gt] : 0.f;
  }
  __syncthreads();
  float acc[NBC];
#pragma unroll
  for (int c = 0; c < NBC; ++c) acc[c] = 0.f;
#pragma unroll 4
  for (int k = 0; k < KF; ++k) {
    float xv = xs[tid + k];
#pragma unroll
    for (int c = 0; c < NBC; ++c) acc[c] = fmaf(bck[c * KF + k], xv, acc[c]);
  }
#pragma unroll
  for (int c = 0; c < NBC; ++c)
    xfg[((size_t)b * NBC + c) * TT + t0 + tid] = __float2half(acc[c]);
}

// LDS pool (bytes):
//  [0,     9720)  u ring u32 [NAC][RINGP], packed (uA,uB) f16 (x overlay in conv mode)
//  [9720, 14648)  xf fp16 [NBC][XPAD]
//  [14656,14912)  acr u32 [64]
//  [14912,14976)  relr u32 [16]
#define POOL_BYTES 14976

template<bool PRECONV>
__global__ __launch_bounds__(64)
void bcn_kernel(const float* __restrict__ x,
                const float* __restrict__ bck,
                const float* __restrict__ lss,
                const float* __restrict__ soff,
                const float* __restrict__ lbaw,
                const float* __restrict__ ltr,
                const float* __restrict__ ltd,
                const float* __restrict__ lass,
                const float* __restrict__ asoff,
                const float* __restrict__ labw,
                const float* __restrict__ oscale,
                const __half* __restrict__ xfg,
                float* __restrict__ out)
{
  __shared__ __align__(16) char pool[POOL_BYTES];
  unsigned* u_ring = (unsigned*)pool;                  // [NAC][RINGP]
  float*    x_lds  = (float*)pool;                     // overlay (conv mode only)
  __half*   xf_lds = (__half*)(pool + 9720);           // [NBC][XPAD]
  unsigned* acr    = (unsigned*)(pool + 14656);        // [64]
  unsigned* relr   = (unsigned*)(pool + 14912);        // [16]

  const int lid   = threadIdx.x;
  const int c16   = lid & 15;
  const int q     = lid >> 4;
  const float rowm = (q & 1) ? 0.f : 1.f;   // rows 0,2: BCN; rows 1,3: LNR
  const int blk   = blockIdx.x;
  const int b     = blk >> 5;            // batch
  const int p     = blk & 31;            // chunk pair
  const int t0A   = p * (2 * CHC);
  const int t_begin = t0A - WU;

  if constexpr (PRECONV) {
    // ---- copy precomputed xf slice into LDS (clamp t<0; p==0 only) ----
    const __half* src = xfg + (size_t)b * NBC * TT;
    if (p == 0) {
      for (int e = lid; e < NBC * SPAN; e += 64) {
        int c = e / SPAN, i = e - c * SPAN;
        int gt = t_begin + i; if (gt < 0) gt = 0;   // chain-A warm garbage, reset later
        xf_lds[c * XPAD + i] = src[(size_t)c * TT + gt];
      }
    } else {
      for (int c = 0; c < NBC; ++c) {
        if (lid < SPAN / 4) {      // 43 uint2 per row; t_begin mult of 4 -> 8B aligned
          uint2 v = *(const uint2*)(src + (size_t)c * TT + t_begin + 4 * lid);
          *(uint2*)&xf_lds[c * XPAD + 4 * lid] = v;
        }
      }
    }
  } else {
    // ---- in-kernel conv (fallback when d_ws too small) ----
    for (int i = lid; i < SPAN + KF - 1; i += 64) {
      int gt = t_begin - (KF - 1) + i;
      x_lds[i] = (gt >= 0) ? x[b * TT + gt] : 0.f;
    }
    __syncthreads();
    for (int ib = 0; ib < 3; ++ib) {
      int tau = lid + (ib << 6);
      if (tau < SPAN) {
        float acc[NBC];
#pragma unroll
        for (int c = 0; c < NBC; ++c) acc[c] = 0.f;
#pragma unroll 4
        for (int k = 0; k < KF; ++k) {
          float xv = x_lds[tau + k];
#pragma unroll
          for (int c = 0; c < NBC; ++c) acc[c] = fmaf(bck[c * KF + k], xv, acc[c]);
        }
#pragma unroll
        for (int c = 0; c < NBC; ++c) xf_lds[c * XPAD + tau] = __float2half(acc[c]);
      }
    }
    __syncthreads();
  }

  // ---- zero u ring + acr + relr ----
  for (int i = lid; i < NAC * RINGP; i += 64) u_ring[i] = 0u;
  if (lid < 64) acr[lid] = 0u;
  if (lid < 16) relr[lid] = 0u;

  // ---- per-lane parameters ----
  float slope2 = 0.f, soff2 = 0.f, osc_c = 0.f;
  f2 poolP; poolP.x = 1.f; poolP.y = 1.f;
  f2 SA; SA.x = 0.f; SA.y = 0.f;
  f2 SB; SB.x = 0.f; SB.y = 0.f;
  f2 rv2, cn2, co2; rv2.x = rv2.y = cn2.x = cn2.y = co2.x = co2.y = 0.f;
  float Adrv2 = 0.f, Boff2 = 0.f;
  v2h wfbh[16];
  v2h wuh[NBC];
  f2 yst[4], fst[4];
  unsigned acst[4];

#pragma unroll
  for (int j = 0; j < 16; ++j) wfbh[j] = pk2(0.f, 0.f);
#pragma unroll
  for (int c = 0; c < NBC; ++c) wuh[c] = pk2(0.f, 0.f);

  if (c16 < NBC) {
    float sl = expf(lss[c16]);
    slope2 = sl * LOG2E;
    soff2  = soff[c16] * sl * LOG2E;
    osc_c  = oscale[c16];
#pragma unroll
    for (int j = 0; j < 16; ++j) {
      int a = 16 * q + j;
      if (a < NAC) { float w = -expf(labw[c16 * NAC + a]); wfbh[j] = pk2(w, w); }
    }
  }
  if (lid < NAC) {
    float tr = expf(ltr[lid]);
    float td = expf(ltd[lid]);
    float a1 = 1.f / td;
    float gg = (td + tr) / (td * tr);
    rv2.x = expf(-a1 * 0.015625f);  rv2.y = expf(-gg * 0.015625f);
    cn2.x = expf(-a1 * 0.003125f);  cn2.y = expf(-gg * 0.003125f);
    co2.x = expf(-a1 * 0.815625f);  co2.y = expf(-gg * 0.815625f);
    float nrm = 0.f;
    for (int k = 0; k < KF; ++k) {
      float kt = 0.8f - (float)k * 0.015625f;
      float d = expf(-a1 * kt) - expf(-gg * kt);
      nrm = fmaf(d, d, nrm);
    }
    float inorm  = 1.f / sqrtf(nrm);
    float aslope = expf(lass[lid]);
    Adrv2 = aslope * inorm * LOG2E;
    Boff2 = aslope * asoff[lid] * LOG2E;
#pragma unroll
    for (int c = 0; c < NBC; ++c) {
      float w = expf(lbaw[lid * NBC + c]);
      wuh[c] = pk2(w, w);
    }
  }

  float* yb  = out;
  float* fbp = out + (size_t)BB * TT * NBC;
  float* acp = out + 2 * (size_t)BB * TT * NBC;
  float* ylp = out + 2 * (size_t)BB * TT * NBC + (size_t)BB * TT * NAC;

  __syncthreads();

  auto step = [&](int slot4, int rslot, float xfA, float xfB, float uoA, float uoB,
                  bool emit) __attribute__((always_inline)) {
    float mzA = fmaf(-Adrv2, SA.x - SA.y, Boff2);
    float mzB = fmaf(-Adrv2, SB.x - SB.y, Boff2);
    float acA = __fdividef(1.f, 1.f + exp2_f(mzA));
    float acB = __fdividef(1.f, 1.f + exp2_f(mzB));
    if (lid < NAC) acr[lid] = bcu(pk2(acA, acB));

    const uint4* ab = (const uint4*)(acr + (q << 4));
    uint4 A0 = ab[0], A1 = ab[1], A2 = ab[2], A3 = ab[3];
    v2h g0 = wfbh[0] * bch(A0.x);
    v2h g1 = wfbh[1] * bch(A0.y);
    g0 += wfbh[2]  * bch(A0.z);  g1 += wfbh[3]  * bch(A0.w);
    g0 += wfbh[4]  * bch(A1.x);  g1 += wfbh[5]  * bch(A1.y);
    g0 += wfbh[6]  * bch(A1.z);  g1 += wfbh[7]  * bch(A1.w);
    g0 += wfbh[8]  * bch(A2.x);  g1 += wfbh[9]  * bch(A2.y);
    g0 += wfbh[10] * bch(A2.z);  g1 += wfbh[11] * bch(A2.w);
    g0 += wfbh[12] * bch(A3.x);  g1 += wfbh[13] * bch(A3.y);
    g0 += wfbh[14] * bch(A3.z);  g1 += wfbh[15] * bch(A3.w);
    v2h gs = xsum32h(xsum16h(g0 + g1));
    float fbA = (float)gs[0], fbB = (float)gs[1];

    float mA = fmaf(-slope2, fmaf(rowm, fbA, xfA), soff2);
    float mB = fmaf(-slope2, fmaf(rowm, fbB, xfB), soff2);
    f2 pv;
    pv.x = __fdividef(1.f, 1.f + exp2_f(mA));
    pv.y = __fdividef(1.f, 1.f + exp2_f(mB));
    f2 p2 = poolP * (1.f - RHO) + RHO;
    f2 relP = pv * p2;
    poolP = p2 - relP;
    if (lid < NBC) relr[lid] = bcu(pk2(relP.x, relP.y));
    if (emit) {
      yst[slot4] = relP * osc_c;
      f2 t; t.x = fbA; t.y = fbB; fst[slot4] = t;
      acst[slot4] = bcu(pk2(acA, acB));
    }

    const uint4* rb = (const uint4*)relr;
    uint4 R0 = rb[0], R1 = rb[1], R2 = rb[2], R3 = rb[3];
    v2h h0 = wuh[0] * bch(R0.x);
    v2h h1 = wuh[1] * bch(R0.y);
    h0 += wuh[2]  * bch(R0.z);  h1 += wuh[3]  * bch(R0.w);
    h0 += wuh[4]  * bch(R1.x);  h1 += wuh[5]  * bch(R1.y);
    h0 += wuh[6]  * bch(R1.z);  h1 += wuh[7]  * bch(R1.w);
    h0 += wuh[8]  * bch(R2.x);  h1 += wuh[9]  * bch(R2.y);
    h0 += wuh[10] * bch(R2.z);  h1 += wuh[11] * bch(R2.w);
    h0 += wuh[12] * bch(R3.x);  h1 += wuh[13] * bch(R3.y);
    v2h uh = h0 + h1;
    float uA = (float)uh[0], uB = (float)uh[1];
    if (lid < NAC) {
      u_ring[lid * RINGP + rslot] = bcu(uh);
      SA = SA * rv2 + (cn2 * uA - co2 * uoA);
      SB = SB * rv2 + (cn2 * uB - co2 * uoB);
    }
  };

  auto group = [&](int s4, int r4, bool emit) __attribute__((always_inline)) {
    uint2 xa = *(const uint2*)&xf_lds[c16 * XPAD + s4];
    uint2 xb = *(const uint2*)&xf_lds[c16 * XPAD + s4 + CHC];
    int roff = ((lid < NAC) ? lid : 0) * RINGP + r4;
    uint2 ur01 = *(const uint2*)&u_ring[roff];
    uint2 ur23 = *(const uint2*)&u_ring[roff + 2];
    v2h xA01 = bch(xa.x), xA23 = bch(xa.y);
    v2h xB01 = bch(xb.x), xB23 = bch(xb.y);
    v2h u0 = bch(ur01.x), u1 = bch(ur01.y), u2 = bch(ur23.x), u3 = bch(ur23.y);
    step(0, r4 + 0, (float)xA01[0], (float)xB01[0], (float)u0[0], (float)u0[1], emit);
    step(1, r4 + 1, (float)xA01[1], (float)xB01[1], (float)u1[0], (float)u1[1], emit);
    step(2, r4 + 2, (float)xA23[0], (float)xB23[0], (float)u2[0], (float)u2[1], emit);
    step(3, r4 + 3, (float)xA23[1], (float)xB23[1], (float)u3[0], (float)u3[1], emit);
  };

  // ---- warm phase ----
  int r4 = 0;
  for (int s4 = 0; s4 < WU; s4 += 4) {
    group(s4, r4, false);
    r4 += 4; if (r4 == RING) r4 = 0;
  }

  // chunk-0 exact start: reset chain A state + zero its ring halves
  if (p == 0) {
    SA.x = 0.f; SA.y = 0.f;
    poolP.x = 1.f;
    for (int i = lid; i < NAC * RINGP; i += 64) u_ring[i] &= 0xFFFF0000u;
  }

  // ---- emit phase ----
  for (int s4 = WU; s4 < NTW; s4 += 4) {
    group(s4, r4, true);
    r4 += 4; if (r4 == RING) r4 = 0;

    int tgA = t0A + (s4 - WU);
    size_t baseA = (size_t)b * TT + tgA;
    if (lid < NBC) {                       // row 0: y_bcn + fb
      size_t ob = baseA * NBC + lid;
#pragma unroll
      for (int sl = 0; sl < 4; ++sl) {
        yb [ob + sl * NBC]                     = yst[sl].x;
        yb [ob + (size_t)CHC * NBC + sl * NBC] = yst[sl].y;
        fbp[ob + sl * NBC]                     = fst[sl].x;
        fbp[ob + (size_t)CHC * NBC + sl * NBC] = fst[sl].y;
      }
    } else if (lid >= 16 && lid < 16 + NBC) {  // row 1: y_lnr
      size_t ob = baseA * NBC + (lid - 16);
#pragma unroll
      for (int sl = 0; sl < 4; ++sl) {
        ylp[ob + sl * NBC]                     = yst[sl].x;
        ylp[ob + (size_t)CHC * NBC + sl * NBC] = yst[sl].y;
      }
    }
    if (lid < NAC) {
      size_t oa = baseA * NAC + lid;
#pragma unroll
      for (int sl = 0; sl < 4; ++sl) {
        v2h h = bch(acst[sl]);
        acp[oa + sl * NAC]                     = (float)h[0];
        acp[oa + (size_t)CHC * NAC + sl * NAC] = (float)h[1];
      }
    }
  }
}

extern "C" void kernel_launch(void* const* d_in, const int* in_sizes, int n_in,
                              void* d_out, int out_size, void* d_ws, size_t ws_size,
                              hipStream_t stream) {
  (void)in_sizes; (void)n_in; (void)out_size;
  const float* x    = (const float*)d_in[0];
  const float* bck  = (const float*)d_in[1];
  if (ws_size >= XF_BYTES) {
    __half* xfg = (__half*)d_ws;
    conv_kernel<<<dim3(BB * 16), dim3(256), 0, stream>>>(x, bck, xfg);
    bcn_kernel<true><<<dim3(BB * NPAIR), dim3(64), 0, stream>>>(
        x, bck, (const float*)d_in[2], (const float*)d_in[3], (const float*)d_in[4],
        (const float*)d_in[5], (const float*)d_in[6], (const float*)d_in[7],
        (const float*)d_in[8], (const float*)d_in[9], (const float*)d_in[10],
        xfg, (float*)d_out);
  } else {
    bcn_kernel<false><<<dim3(BB * NPAIR), dim3(64), 0, stream>>>(
        x, bck, (const float*)d_in[2], (const float*)d_in[3], (const float*)d_in[4],
        (const float*)d_in[5], (const float*)d_in[6], (const float*)d_in[7],
        (const float*)d_in[8], (const float*)d_in[9], (const float*)d_in[10],
        (const __half*)nullptr, (float*)d_out);
  }
}

// Round 16
// 91.242 us; speedup vs baseline: 1.0678x; 1.0678x over previous
//
#include <hip/hip_runtime.h>
#include <hip/hip_fp16.h>

#define NBC 14
#define NAC 45
#define KF  52
#define RHO 0.05f
#define TT  4096
#define BB  64
#define CHC 64           // outputs per chain
#define WU  44           // warmup steps
#define NPAIR 32         // chunk pairs per batch
#define NTW (WU + CHC)   // 108 steps per chain
#define SPAN (WU + 2*CHC)// 172: xf range covers both chains
#define XPAD 176         // xf row stride (halfs), mult of 4
#define LOG2E 1.44269504f
#define XF_BYTES ((size_t)BB * NBC * TT * 2)

typedef __fp16 v2h __attribute__((ext_vector_type(2)));
typedef float  f2  __attribute__((ext_vector_type(2)));
typedef int    i2v __attribute__((ext_vector_type(2)));

__device__ __forceinline__ v2h bch(unsigned u) { return __builtin_bit_cast(v2h, u); }
__device__ __forceinline__ unsigned bcu(v2h h) { return __builtin_bit_cast(unsigned, h); }
__device__ __forceinline__ v2h pk2(float lo, float hi) {
#if __has_builtin(__builtin_amdgcn_cvt_pkrtz)
  return __builtin_bit_cast(v2h, __builtin_amdgcn_cvt_pkrtz(lo, hi));
#else
  v2h r; r[0] = (__fp16)lo; r[1] = (__fp16)hi; return r;
#endif
}
__device__ __forceinline__ v2h xsum16h(v2h v) {
#if __has_builtin(__builtin_amdgcn_permlane16_swap)
  i2v r = __builtin_amdgcn_permlane16_swap((int)bcu(v), (int)bcu(v), false, false);
  return bch((unsigned)r[0]) + bch((unsigned)r[1]);
#else
  return v + bch((unsigned)__builtin_amdgcn_ds_swizzle((int)bcu(v), (16 << 10) | 0x1f));
#endif
}
__device__ __forceinline__ v2h xsum32h(v2h v) {
#if __has_builtin(__builtin_amdgcn_permlane32_swap)
  i2v r = __builtin_amdgcn_permlane32_swap((int)bcu(v), (int)bcu(v), false, false);
  return bch((unsigned)r[0]) + bch((unsigned)r[1]);
#else
  return v + bch((unsigned)__shfl_xor((int)bcu(v), 32));
#endif
}
__device__ __forceinline__ float exp2_f(float x) {
#if __has_builtin(__builtin_amdgcn_exp2f)
  return __builtin_amdgcn_exp2f(x);
#else
  return exp2f(x);
#endif
}

// ---------------- conv pre-pass: xf[b][c][t] for all t ----------------
__global__ __launch_bounds__(256)
void conv_kernel(const float* __restrict__ x, const float* __restrict__ bck,
                 __half* __restrict__ xfg) {
  __shared__ float xs[256 + KF];        // tile + halo
  const int tid  = threadIdx.x;
  const int b    = blockIdx.x >> 4;     // 16 tiles of 256
  const int t0   = (blockIdx.x & 15) << 8;
  for (int i = tid; i < 256 + KF - 1; i += 256) {
    int gt = t0 - (KF - 1) + i;
    xs[i] = (gt >= 0) ? x[b * TT + gt] : 0.f;
  }
  __syncthreads();
  float acc[NBC];
#pragma unroll
  for (int c = 0; c < NBC; ++c) acc[c] = 0.f;
#pragma unroll 4
  for (int k = 0; k < KF; ++k) {
    float xv = xs[tid + k];
#pragma unroll
    for (int c = 0; c < NBC; ++c) acc[c] = fmaf(bck[c * KF + k], xv, acc[c]);
  }
#pragma unroll
  for (int c = 0; c < NBC; ++c)
    xfg[((size_t)b * NBC + c) * TT + t0 + tid] = __float2half(acc[c]);
}

// LDS pool (bytes):
//  [0,    4928)  xf fp16 [NBC][XPAD]
//  [4928, 5184)  acr u32 [64]   (entries 45..63 stay zero; 16B aligned)
//  [5184, 5248)  relr u32 [16]  (entries 14,15 stay zero)
//  [5248, 6144)  x slice f32 [224]  (in-kernel conv fallback only)
#define POOL_BYTES 6144

template<bool PRECONV>
__global__ __launch_bounds__(64)
void bcn_kernel(const float* __restrict__ x,
                const float* __restrict__ bck,
                const float* __restrict__ lss,
                const float* __restrict__ soff,
                const float* __restrict__ lbaw,
                const float* __restrict__ ltr,
                const float* __restrict__ ltd,
                const float* __restrict__ lass,
                const float* __restrict__ asoff,
                const float* __restrict__ labw,
                const float* __restrict__ oscale,
                const __half* __restrict__ xfg,
                float* __restrict__ out)
{
  __shared__ __align__(16) char pool[POOL_BYTES];
  __half*   xf_lds = (__half*)pool;                    // [NBC][XPAD]
  unsigned* acr    = (unsigned*)(pool + 4928);         // [64]
  unsigned* relr   = (unsigned*)(pool + 5184);         // [16]
  float*    x_lds  = (float*)(pool + 5248);            // conv fallback only

  const int lid   = threadIdx.x;
  const int c16   = lid & 15;
  const int q     = lid >> 4;
  const float rowm = (q & 1) ? 0.f : 1.f;   // rows 0,2: BCN; rows 1,3: LNR
  const int blk   = blockIdx.x;
  const int b     = blk >> 5;            // batch
  const int p     = blk & 31;            // chunk pair
  const int t0A   = p * (2 * CHC);
  const int t_begin = t0A - WU;

  if constexpr (PRECONV) {
    // ---- copy precomputed xf slice into LDS (clamp t<0; p==0 only) ----
    const __half* src = xfg + (size_t)b * NBC * TT;
    if (p == 0) {
      for (int e = lid; e < NBC * SPAN; e += 64) {
        int c = e / SPAN, i = e - c * SPAN;
        int gt = t_begin + i; if (gt < 0) gt = 0;   // chain-A warm garbage, reset later
        xf_lds[c * XPAD + i] = src[(size_t)c * TT + gt];
      }
    } else {
      for (int c = 0; c < NBC; ++c) {
        if (lid < SPAN / 4) {
          uint2 v = *(const uint2*)(src + (size_t)c * TT + t_begin + 4 * lid);
          *(uint2*)&xf_lds[c * XPAD + 4 * lid] = v;
        }
      }
    }
  } else {
    // ---- in-kernel conv (fallback when d_ws too small) ----
    for (int i = lid; i < SPAN + KF - 1; i += 64) {
      int gt = t_begin - (KF - 1) + i;
      x_lds[i] = (gt >= 0) ? x[b * TT + gt] : 0.f;
    }
    __syncthreads();
    for (int ib = 0; ib < 3; ++ib) {
      int tau = lid + (ib << 6);
      if (tau < SPAN) {
        float acc[NBC];
#pragma unroll
        for (int c = 0; c < NBC; ++c) acc[c] = 0.f;
#pragma unroll 4
        for (int k = 0; k < KF; ++k) {
          float xv = x_lds[tau + k];
#pragma unroll
          for (int c = 0; c < NBC; ++c) acc[c] = fmaf(bck[c * KF + k], xv, acc[c]);
        }
#pragma unroll
        for (int c = 0; c < NBC; ++c) xf_lds[c * XPAD + tau] = __float2half(acc[c]);
      }
    }
    __syncthreads();
  }

  // ---- zero acr + relr ----
  if (lid < 64) acr[lid] = 0u;
  if (lid < 16) relr[lid] = 0u;

  // ---- per-lane parameters ----
  float slope2 = 0.f, soff2 = 0.f, osc_c = 0.f;
  f2 poolP; poolP.x = 1.f; poolP.y = 1.f;
  f2 SA; SA.x = 0.f; SA.y = 0.f;      // (S1,S2) chain A — infinite-history states
  f2 SB; SB.x = 0.f; SB.y = 0.f;
  f2 rv2, cn2; rv2.x = rv2.y = cn2.x = cn2.y = 0.f;
  float Adrv2 = 0.f, Boff2 = 0.f;
  v2h wfbh[16];
  v2h wuh[NBC];
  f2 yst[4], fst[4];
  unsigned acst[4];

#pragma unroll
  for (int j = 0; j < 16; ++j) wfbh[j] = pk2(0.f, 0.f);
#pragma unroll
  for (int c = 0; c < NBC; ++c) wuh[c] = pk2(0.f, 0.f);

  if (c16 < NBC) {
    float sl = expf(lss[c16]);
    slope2 = sl * LOG2E;
    soff2  = soff[c16] * sl * LOG2E;
    osc_c  = oscale[c16];
#pragma unroll
    for (int j = 0; j < 16; ++j) {
      int a = 16 * q + j;
      if (a < NAC) { float w = -expf(labw[c16 * NAC + a]); wfbh[j] = pk2(w, w); }
    }
  }
  if (lid < NAC) {
    float tr = expf(ltr[lid]);
    float td = expf(ltd[lid]);
    float a1 = 1.f / td;
    float gg = (td + tr) / (td * tr);
    rv2.x = expf(-a1 * 0.015625f);  rv2.y = expf(-gg * 0.015625f);
    cn2.x = expf(-a1 * 0.003125f);  cn2.y = expf(-gg * 0.003125f);
    float nrm = 0.f;
    for (int k = 0; k < KF; ++k) {
      float kt = 0.8f - (float)k * 0.015625f;
      float d = expf(-a1 * kt) - expf(-gg * kt);
      nrm = fmaf(d, d, nrm);
    }
    float inorm  = 1.f / sqrtf(nrm);
    float aslope = expf(lass[lid]);
    Adrv2 = aslope * inorm * LOG2E;
    Boff2 = aslope * asoff[lid] * LOG2E;
#pragma unroll
    for (int c = 0; c < NBC; ++c) {
      float w = expf(lbaw[lid * NBC + c]);
      wuh[c] = pk2(w, w);
    }
  }

  float* yb  = out;
  float* fbp = out + (size_t)BB * TT * NBC;
  float* acp = out + 2 * (size_t)BB * TT * NBC;
  float* ylp = out + 2 * (size_t)BB * TT * NBC + (size_t)BB * TT * NAC;

  __syncthreads();

  auto step = [&](int slot4, float xfA, float xfB, bool emit)
      __attribute__((always_inline)) {
    float mzA = fmaf(-Adrv2, SA.x - SA.y, Boff2);
    float mzB = fmaf(-Adrv2, SB.x - SB.y, Boff2);
    float acA = __fdividef(1.f, 1.f + exp2_f(mzA));
    float acB = __fdividef(1.f, 1.f + exp2_f(mzB));
    if (lid < NAC) acr[lid] = bcu(pk2(acA, acB));

    const uint4* ab = (const uint4*)(acr + (q << 4));
    uint4 A0 = ab[0], A1 = ab[1], A2 = ab[2], A3 = ab[3];
    v2h g0 = wfbh[0] * bch(A0.x);
    v2h g1 = wfbh[1] * bch(A0.y);
    g0 += wfbh[2]  * bch(A0.z);  g1 += wfbh[3]  * bch(A0.w);
    g0 += wfbh[4]  * bch(A1.x);  g1 += wfbh[5]  * bch(A1.y);
    g0 += wfbh[6]  * bch(A1.z);  g1 += wfbh[7]  * bch(A1.w);
    g0 += wfbh[8]  * bch(A2.x);  g1 += wfbh[9]  * bch(A2.y);
    g0 += wfbh[10] * bch(A2.z);  g1 += wfbh[11] * bch(A2.w);
    g0 += wfbh[12] * bch(A3.x);  g1 += wfbh[13] * bch(A3.y);
    g0 += wfbh[14] * bch(A3.z);  g1 += wfbh[15] * bch(A3.w);
    v2h gs = xsum32h(xsum16h(g0 + g1));
    float fbA = (float)gs[0], fbB = (float)gs[1];

    float mA = fmaf(-slope2, fmaf(rowm, fbA, xfA), soff2);
    float mB = fmaf(-slope2, fmaf(rowm, fbB, xfB), soff2);
    f2 pv;
    pv.x = __fdividef(1.f, 1.f + exp2_f(mA));
    pv.y = __fdividef(1.f, 1.f + exp2_f(mB));
    f2 p2 = poolP * (1.f - RHO) + RHO;
    f2 relP = pv * p2;
    poolP = p2 - relP;
    if (lid < NBC) relr[lid] = bcu(pk2(relP.x, relP.y));
    if (emit) {
      yst[slot4] = relP * osc_c;
      f2 t; t.x = fbA; t.y = fbB; fst[slot4] = t;
      acst[slot4] = bcu(pk2(acA, acB));
    }

    const uint4* rb = (const uint4*)relr;
    uint4 R0 = rb[0], R1 = rb[1], R2 = rb[2], R3 = rb[3];
    v2h h0 = wuh[0] * bch(R0.x);
    v2h h1 = wuh[1] * bch(R0.y);
    h0 += wuh[2]  * bch(R0.z);  h1 += wuh[3]  * bch(R0.w);
    h0 += wuh[4]  * bch(R1.x);  h1 += wuh[5]  * bch(R1.y);
    h0 += wuh[6]  * bch(R1.z);  h1 += wuh[7]  * bch(R1.w);
    h0 += wuh[8]  * bch(R2.x);  h1 += wuh[9]  * bch(R2.y);
    h0 += wuh[10] * bch(R2.z);  h1 += wuh[11] * bch(R2.w);
    h0 += wuh[12] * bch(R3.x);  h1 += wuh[13] * bch(R3.y);
    v2h uh = h0 + h1;
    // infinite-history exponential states (tail beyond kt=0.8 is <=3e-4 in ac)
    SA = SA * rv2 + cn2 * (float)uh[0];
    SB = SB * rv2 + cn2 * (float)uh[1];
  };

  auto group = [&](int s4, bool emit) __attribute__((always_inline)) {
    uint2 xa = *(const uint2*)&xf_lds[c16 * XPAD + s4];
    uint2 xb = *(const uint2*)&xf_lds[c16 * XPAD + s4 + CHC];
    v2h xA01 = bch(xa.x), xA23 = bch(xa.y);
    v2h xB01 = bch(xb.x), xB23 = bch(xb.y);
    step(0, (float)xA01[0], (float)xB01[0], emit);
    step(1, (float)xA01[1], (float)xB01[1], emit);
    step(2, (float)xA23[0], (float)xB23[0], emit);
    step(3, (float)xA23[1], (float)xB23[1], emit);
  };

  // ---- warm phase ----
  for (int s4 = 0; s4 < WU; s4 += 4) group(s4, false);

  // chunk-0 exact start: reset chain A state (true history is empty)
  if (p == 0) {
    SA.x = 0.f; SA.y = 0.f;
    poolP.x = 1.f;
  }

  // ---- emit phase ----
  for (int s4 = WU; s4 < NTW; s4 += 4) {
    group(s4, true);

    int tgA = t0A + (s4 - WU);
    size_t baseA = (size_t)b * TT + tgA;
    if (lid < NBC) {                       // row 0: y_bcn + fb
      size_t ob = baseA * NBC + lid;
#pragma unroll
      for (int sl = 0; sl < 4; ++sl) {
        yb [ob + sl * NBC]                     = yst[sl].x;
        yb [ob + (size_t)CHC * NBC + sl * NBC] = yst[sl].y;
        fbp[ob + sl * NBC]                     = fst[sl].x;
        fbp[ob + (size_t)CHC * NBC + sl * NBC] = fst[sl].y;
      }
    } else if (lid >= 16 && lid < 16 + NBC) {  // row 1: y_lnr
      size_t ob = baseA * NBC + (lid - 16);
#pragma unroll
      for (int sl = 0; sl < 4; ++sl) {
        ylp[ob + sl * NBC]                     = yst[sl].x;
        ylp[ob + (size_t)CHC * NBC + sl * NBC] = yst[sl].y;
      }
    }
    if (lid < NAC) {
      size_t oa = baseA * NAC + lid;
#pragma unroll
      for (int sl = 0; sl < 4; ++sl) {
        v2h h = bch(acst[sl]);
        acp[oa + sl * NAC]                     = (float)h[0];
        acp[oa + (size_t)CHC * NAC + sl * NAC] = (float)h[1];
      }
    }
  }
}

extern "C" void kernel_launch(void* const* d_in, const int* in_sizes, int n_in,
                              void* d_out, int out_size, void* d_ws, size_t ws_size,
                              hipStream_t stream) {
  (void)in_sizes; (void)n_in; (void)out_size;
  const float* x    = (const float*)d_in[0];
  const float* bck  = (const float*)d_in[1];
  if (ws_size >= XF_BYTES) {
    __half* xfg = (__half*)d_ws;
    conv_kernel<<<dim3(BB * 16), dim3(256), 0, stream>>>(x, bck, xfg);
    bcn_kernel<true><<<dim3(BB * NPAIR), dim3(64), 0, stream>>>(
        x, bck, (const float*)d_in[2], (const float*)d_in[3], (const float*)d_in[4],
        (const float*)d_in[5], (const float*)d_in[6], (const float*)d_in[7],
        (const float*)d_in[8], (const float*)d_in[9], (const float*)d_in[10],
        xfg, (float*)d_out);
  } else {
    bcn_kernel<false><<<dim3(BB * NPAIR), dim3(64), 0, stream>>>(
        x, bck, (const float*)d_in[2], (const float*)d_in[3], (const float*)d_in[4],
        (const float*)d_in[5], (const float*)d_in[6], (const float*)d_in[7],
        (const float*)d_in[8], (const float*)d_in[9], (const float*)d_in[10],
        (const __half*)nullptr, (float*)d_out);
  }
}